// Round 8
// baseline (185.635 us; speedup 1.0000x reference)
//
#include <hip/hip_runtime.h>

// Problem: inputs [8192, 8192] f32. Semantics: idx = nonzero(x); out = idx.sum(0) -> int64 [2]
//   out[0] = sum of row-index i over nonzeros; out[1] = sum of col-index j over nonzeros.
// Harness reads d_out as int32 (int64 ref wrapped via astype(np.int32)) -> write low 32 bits.
//
// R5 lesson: same-cache-line atomic RMWs serialize at ~7ns each -> never funnel per-block
//            atomics into one line. R6: straight-line loads schedule deep; rolled loops don't.
// R7: 16-deep straight-line, 2-kernel = 49.7 us. R8: fuse finalize via TWO-LEVEL done
//     counter (32 sub-counters on separate lines + 1 master) -> no RMW storm, one dispatch.

#define DIM1 8192u
#define NBLK 4096u
#define TPB  256u
// 4096 blocks * 256 thr * 16 float4 = 16777216 float4s = exact cover of 8192x8192 f32.

typedef unsigned long long u64;

__device__ __forceinline__ void nz_accum(float4 v, unsigned q,
                                         unsigned& si, unsigned& sj) {
    unsigned i  = q >> 11;                // row index: q / (8192/4)
    unsigned jb = (q << 2) & (DIM1 - 1u); // col index of v.x
    if (v.x != 0.0f) { si += i; sj += jb;      }
    if (v.y != 0.0f) { si += i; sj += jb + 1u; }
    if (v.z != 0.0f) { si += i; sj += jb + 2u; }
    if (v.w != 0.0f) { si += i; sj += jb + 3u; }
}

// ws layout (u64 units):
//   [0 .. 4095]   per-block packed partials (lo32 = si, hi32 = sj) — plain stores
//   [4096 + g*8]  sub-counter for group g (g = blockIdx & 31), own 64B line each
//   [4096 + 256]  master counter
// Counters zeroed by hipMemsetAsync each call (d_ws is poisoned once before timing).

__global__ void nz_fused(const float4* __restrict__ in, u64* __restrict__ ws,
                         int* __restrict__ out) {
    const unsigned q0 = blockIdx.x * 4096u + threadIdx.x;

    // 16 independent coalesced loads, straight-line (R7-proven main body)
    float4 v0  = in[q0];
    float4 v1  = in[q0 + 1u  * 256u];
    float4 v2  = in[q0 + 2u  * 256u];
    float4 v3  = in[q0 + 3u  * 256u];
    float4 v4  = in[q0 + 4u  * 256u];
    float4 v5  = in[q0 + 5u  * 256u];
    float4 v6  = in[q0 + 6u  * 256u];
    float4 v7  = in[q0 + 7u  * 256u];
    float4 v8  = in[q0 + 8u  * 256u];
    float4 v9  = in[q0 + 9u  * 256u];
    float4 v10 = in[q0 + 10u * 256u];
    float4 v11 = in[q0 + 11u * 256u];
    float4 v12 = in[q0 + 12u * 256u];
    float4 v13 = in[q0 + 13u * 256u];
    float4 v14 = in[q0 + 14u * 256u];
    float4 v15 = in[q0 + 15u * 256u];

    unsigned si = 0u, sj = 0u;  // per-thread max ~524K, fits u32
    nz_accum(v0,  q0,              si, sj);
    nz_accum(v1,  q0 + 1u  * 256u, si, sj);
    nz_accum(v2,  q0 + 2u  * 256u, si, sj);
    nz_accum(v3,  q0 + 3u  * 256u, si, sj);
    nz_accum(v4,  q0 + 4u  * 256u, si, sj);
    nz_accum(v5,  q0 + 5u  * 256u, si, sj);
    nz_accum(v6,  q0 + 6u  * 256u, si, sj);
    nz_accum(v7,  q0 + 7u  * 256u, si, sj);
    nz_accum(v8,  q0 + 8u  * 256u, si, sj);
    nz_accum(v9,  q0 + 9u  * 256u, si, sj);
    nz_accum(v10, q0 + 10u * 256u, si, sj);
    nz_accum(v11, q0 + 11u * 256u, si, sj);
    nz_accum(v12, q0 + 12u * 256u, si, sj);
    nz_accum(v13, q0 + 13u * 256u, si, sj);
    nz_accum(v14, q0 + 14u * 256u, si, sj);
    nz_accum(v15, q0 + 15u * 256u, si, sj);

    // wave64 reduce (u32; wave partial max ~33.5M, fits)
    for (int off = 32; off > 0; off >>= 1) {
        si += __shfl_down(si, off, 64);
        sj += __shfl_down(sj, off, 64);
    }

    __shared__ unsigned s_i[4], s_j[4];
    __shared__ int s_last;
    const int wave = threadIdx.x >> 6;
    const int lane = threadIdx.x & 63;
    if (lane == 0) { s_i[wave] = si; s_j[wave] = sj; }
    __syncthreads();

    if (threadIdx.x == 0) {
        // block partial max ~134M each, fits u32; pack into one u64, plain store
        unsigned ti = s_i[0] + s_i[1] + s_i[2] + s_i[3];
        unsigned tj = s_j[0] + s_j[1] + s_j[2] + s_j[3];
        ws[blockIdx.x] = ((u64)tj << 32) | (u64)ti;

        int last = 0;
        // level 1: 32 sub-counters on distinct lines, 128 blocks each -> ~0.9us max per line
        u64* sub = ws + NBLK + (u64)(blockIdx.x & 31u) * 8u;
        u64 prev = __hip_atomic_fetch_add(sub, 1ull, __ATOMIC_ACQ_REL,
                                          __HIP_MEMORY_SCOPE_AGENT);
        if (prev == (u64)(NBLK / 32u - 1u)) {          // 127: group complete
            // level 2: master, only 32 RMWs total
            u64* master = ws + NBLK + 256u;
            u64 m = __hip_atomic_fetch_add(master, 1ull, __ATOMIC_ACQ_REL,
                                           __HIP_MEMORY_SCOPE_AGENT);
            if (m == 31u) last = 1;                     // all 4096 partials published
        }
        s_last = last;
    }
    __syncthreads();
    if (!s_last) return;

    // Last block: acquire chain (partial store -> sub release -> master release ->
    // our master acquire) gives transitive happens-before for ALL partial stores.
    // Agent fence so all 256 threads (not just thread 0's wave) see fresh lines.
    __threadfence();

    u64 ti = 0, tj = 0;
#pragma unroll
    for (unsigned s = threadIdx.x; s < NBLK; s += TPB) {  // 16 coalesced u64 loads
        u64 p = ws[s];
        ti += (u64)(unsigned)p;   // lo32 = si partial
        tj += (p >> 32);          // hi32 = sj partial
    }
    for (int off = 32; off > 0; off >>= 1) {
        ti += __shfl_down(ti, off, 64);
        tj += __shfl_down(tj, off, 64);
    }
    __shared__ u64 f_i[4], f_j[4];
    if (lane == 0) { f_i[wave] = ti; f_j[wave] = tj; }
    __syncthreads();
    if (threadIdx.x == 0) {
        u64 a = f_i[0] + f_i[1] + f_i[2] + f_i[3];
        u64 b = f_j[0] + f_j[1] + f_j[2] + f_j[3];
        out[0] = (int)(unsigned)(a & 0xFFFFFFFFull);  // int64 -> int32 wrap
        out[1] = (int)(unsigned)(b & 0xFFFFFFFFull);
    }
}

extern "C" void kernel_launch(void* const* d_in, const int* in_sizes, int n_in,
                              void* d_out, int out_size, void* d_ws, size_t ws_size,
                              hipStream_t stream) {
    const float4* in = (const float4*)d_in[0];
    u64* ws = (u64*)d_ws;   // needs (4096 + 257) * 8 = 34824 bytes
    int* out = (int*)d_out;

    // zero ONLY the counters (257 u64 starting at ws[4096]); partial slots are
    // fully overwritten each call under the release/acquire chain.
    hipMemsetAsync((char*)d_ws + (size_t)NBLK * 8u, 0, 257u * 8u, stream);

    nz_fused<<<NBLK, TPB, 0, stream>>>(in, ws, out);
}

// Round 9
// 111.334 us; speedup vs baseline: 1.6674x; 1.6674x over previous
//
#include <hip/hip_runtime.h>

// Problem: inputs [8192, 8192] f32. Semantics: idx = nonzero(x); out = idx.sum(0) -> int64 [2]
//   out[0] = sum of row-index i over nonzeros; out[1] = sum of col-index j over nonzeros.
// Harness reads d_out as int32 (int64 ref wrapped via astype(np.int32)) -> write low 32 bits.
//
// Session lessons:
//  R5/R8: per-block agent-scope ORDERED atomics / __threadfence emit L2 writeback/inv
//         cache ops (~60ns/block serialized) -> never fence per block. Kernel-boundary
//         implicit release/acquire is cheaper than 4096 explicit ones.
//  R6/R7: straight-line independent float4 loads + private partial slots -> 49.7 us,
//         main kernel ~45 us ~ 6 TB/s (~95% of m13's 6.29 TB/s read ceiling).
//  R9: drop the finalize kernel: RELAXED atomicAdd of u32 block partials directly into
//      d_out (u32 modular add == int64->int32 wrap, exact). No fences, no cache ops;
//      8192 same-line RMWs spread over ~40us are absorbed at ~7ns service each.

#define DIM1 8192u
#define NBLK 4096u
#define TPB  256u
// 4096 blocks * 256 thr * 16 float4 = 16777216 float4s = exact cover of 8192x8192 f32.

__device__ __forceinline__ void nz_accum(float4 v, unsigned q,
                                         unsigned& si, unsigned& sj) {
    unsigned i  = q >> 11;                // row index: q / (8192/4)
    unsigned jb = (q << 2) & (DIM1 - 1u); // col index of v.x
    if (v.x != 0.0f) { si += i; sj += jb;      }
    if (v.y != 0.0f) { si += i; sj += jb + 1u; }
    if (v.z != 0.0f) { si += i; sj += jb + 2u; }
    if (v.w != 0.0f) { si += i; sj += jb + 3u; }
}

__global__ void nz_main(const float4* __restrict__ in, unsigned* __restrict__ out) {
    const unsigned q0 = blockIdx.x * 4096u + threadIdx.x;

    // 16 independent coalesced loads, straight-line (R7-proven body, unchanged)
    float4 v0  = in[q0];
    float4 v1  = in[q0 + 1u  * 256u];
    float4 v2  = in[q0 + 2u  * 256u];
    float4 v3  = in[q0 + 3u  * 256u];
    float4 v4  = in[q0 + 4u  * 256u];
    float4 v5  = in[q0 + 5u  * 256u];
    float4 v6  = in[q0 + 6u  * 256u];
    float4 v7  = in[q0 + 7u  * 256u];
    float4 v8  = in[q0 + 8u  * 256u];
    float4 v9  = in[q0 + 9u  * 256u];
    float4 v10 = in[q0 + 10u * 256u];
    float4 v11 = in[q0 + 11u * 256u];
    float4 v12 = in[q0 + 12u * 256u];
    float4 v13 = in[q0 + 13u * 256u];
    float4 v14 = in[q0 + 14u * 256u];
    float4 v15 = in[q0 + 15u * 256u];

    unsigned si = 0u, sj = 0u;  // per-thread max ~524K, fits u32
    nz_accum(v0,  q0,              si, sj);
    nz_accum(v1,  q0 + 1u  * 256u, si, sj);
    nz_accum(v2,  q0 + 2u  * 256u, si, sj);
    nz_accum(v3,  q0 + 3u  * 256u, si, sj);
    nz_accum(v4,  q0 + 4u  * 256u, si, sj);
    nz_accum(v5,  q0 + 5u  * 256u, si, sj);
    nz_accum(v6,  q0 + 6u  * 256u, si, sj);
    nz_accum(v7,  q0 + 7u  * 256u, si, sj);
    nz_accum(v8,  q0 + 8u  * 256u, si, sj);
    nz_accum(v9,  q0 + 9u  * 256u, si, sj);
    nz_accum(v10, q0 + 10u * 256u, si, sj);
    nz_accum(v11, q0 + 11u * 256u, si, sj);
    nz_accum(v12, q0 + 12u * 256u, si, sj);
    nz_accum(v13, q0 + 13u * 256u, si, sj);
    nz_accum(v14, q0 + 14u * 256u, si, sj);
    nz_accum(v15, q0 + 15u * 256u, si, sj);

    // wave64 reduce (u32; wave partial max ~33.5M, fits)
    for (int off = 32; off > 0; off >>= 1) {
        si += __shfl_down(si, off, 64);
        sj += __shfl_down(sj, off, 64);
    }

    __shared__ unsigned s_i[4], s_j[4];
    const int wave = threadIdx.x >> 6;
    const int lane = threadIdx.x & 63;
    if (lane == 0) { s_i[wave] = si; s_j[wave] = sj; }
    __syncthreads();

    if (threadIdx.x == 0) {
        // Relaxed device-scope atomicAdd, NO fence: u32 modular accumulation into
        // d_out == int64 sum wrapped to int32 (exact). ~8192 RMWs on one line,
        // spread over the kernel's ~40us -> absorbed by the coherence point.
        unsigned ti = s_i[0] + s_i[1] + s_i[2] + s_i[3];
        unsigned tj = s_j[0] + s_j[1] + s_j[2] + s_j[3];
        atomicAdd(&out[0], ti);
        atomicAdd(&out[1], tj);
    }
}

extern "C" void kernel_launch(void* const* d_in, const int* in_sizes, int n_in,
                              void* d_out, int out_size, void* d_ws, size_t ws_size,
                              hipStream_t stream) {
    const float4* in = (const float4*)d_in[0];
    unsigned* out = (unsigned*)d_out;

    // out accumulates across the kernel -> must start at 0 every call
    // (timed replays do NOT re-poison/zero d_out). 8-byte memset node.
    hipMemsetAsync(d_out, 0, 2 * sizeof(unsigned), stream);

    nz_main<<<NBLK, TPB, 0, stream>>>(in, out);
}

// Round 10
// 49.596 us; speedup vs baseline: 3.7430x; 2.2448x over previous
//
#include <hip/hip_runtime.h>

// Problem: inputs [8192, 8192] f32. Semantics: idx = nonzero(x); out = idx.sum(0) -> int64 [2]
//   out[0] = sum of row-index i over nonzeros; out[1] = sum of col-index j over nonzeros.
// Harness reads d_out as int32 (int64 ref wrapped via astype(np.int32)) -> write low 32 bits.
//
// Session lessons (final):
//  - Straight-line independent float4 loads schedule deep (16 in flight); rolled loops
//    collapse to pairwise load/consume (32 VGPR) and lose ~2x BW.
//  - Any per-block same-line RMW protocol loses: relaxed ~7.5ns each (R9, +60us),
//    acq_rel/fence ~60ns each (R5/R8, +130-260us). Plain stores to private slots +
//    a tiny second kernel (kernel-boundary release/acquire) cost only ~4-5us.
//  - This structure: main ~45us ~= 6.0 TB/s effective read (85% of fill-kernel fabric
//    ceiling, L3 serving ~half the 256MiB input). Memory-bound floor.

#define DIM1 8192u
#define NBLK 4096u
#define TPB  256u
// 4096 blocks * 256 thr * 16 float4 = 16777216 float4s = exact cover of 8192x8192 f32.

typedef unsigned long long u64;

__device__ __forceinline__ void nz_accum(float4 v, unsigned q,
                                         unsigned& si, unsigned& sj) {
    unsigned i  = q >> 11;                // row index: q / (8192/4)
    unsigned jb = (q << 2) & (DIM1 - 1u); // col index of v.x
    if (v.x != 0.0f) { si += i; sj += jb;      }
    if (v.y != 0.0f) { si += i; sj += jb + 1u; }
    if (v.z != 0.0f) { si += i; sj += jb + 2u; }
    if (v.w != 0.0f) { si += i; sj += jb + 3u; }
}

__global__ void nz_main(const float4* __restrict__ in, uint2* __restrict__ ws) {
    const unsigned q0 = blockIdx.x * 4096u + threadIdx.x;

    // 16 independent coalesced loads, straight-line, no loop-carried dependence
    float4 v0  = in[q0];
    float4 v1  = in[q0 + 1u  * 256u];
    float4 v2  = in[q0 + 2u  * 256u];
    float4 v3  = in[q0 + 3u  * 256u];
    float4 v4  = in[q0 + 4u  * 256u];
    float4 v5  = in[q0 + 5u  * 256u];
    float4 v6  = in[q0 + 6u  * 256u];
    float4 v7  = in[q0 + 7u  * 256u];
    float4 v8  = in[q0 + 8u  * 256u];
    float4 v9  = in[q0 + 9u  * 256u];
    float4 v10 = in[q0 + 10u * 256u];
    float4 v11 = in[q0 + 11u * 256u];
    float4 v12 = in[q0 + 12u * 256u];
    float4 v13 = in[q0 + 13u * 256u];
    float4 v14 = in[q0 + 14u * 256u];
    float4 v15 = in[q0 + 15u * 256u];

    unsigned si = 0u, sj = 0u;  // per-thread max ~524K, fits u32
    nz_accum(v0,  q0,              si, sj);
    nz_accum(v1,  q0 + 1u  * 256u, si, sj);
    nz_accum(v2,  q0 + 2u  * 256u, si, sj);
    nz_accum(v3,  q0 + 3u  * 256u, si, sj);
    nz_accum(v4,  q0 + 4u  * 256u, si, sj);
    nz_accum(v5,  q0 + 5u  * 256u, si, sj);
    nz_accum(v6,  q0 + 6u  * 256u, si, sj);
    nz_accum(v7,  q0 + 7u  * 256u, si, sj);
    nz_accum(v8,  q0 + 8u  * 256u, si, sj);
    nz_accum(v9,  q0 + 9u  * 256u, si, sj);
    nz_accum(v10, q0 + 10u * 256u, si, sj);
    nz_accum(v11, q0 + 11u * 256u, si, sj);
    nz_accum(v12, q0 + 12u * 256u, si, sj);
    nz_accum(v13, q0 + 13u * 256u, si, sj);
    nz_accum(v14, q0 + 14u * 256u, si, sj);
    nz_accum(v15, q0 + 15u * 256u, si, sj);

    // wave64 reduce (u32; wave partial max ~33.5M, fits)
    for (int off = 32; off > 0; off >>= 1) {
        si += __shfl_down(si, off, 64);
        sj += __shfl_down(sj, off, 64);
    }

    __shared__ unsigned s_i[4], s_j[4];
    const int wave = threadIdx.x >> 6;
    const int lane = threadIdx.x & 63;
    if (lane == 0) { s_i[wave] = si; s_j[wave] = sj; }
    __syncthreads();

    if (threadIdx.x == 0) {
        // block partial max ~134M, fits u32. Private slot: no contention, no atomics.
        unsigned ti = s_i[0] + s_i[1] + s_i[2] + s_i[3];
        unsigned tj = s_j[0] + s_j[1] + s_j[2] + s_j[3];
        ws[blockIdx.x] = make_uint2(ti, tj);   // plain store; fully overwritten every call
    }
}

__global__ void nz_finalize(const uint2* __restrict__ ws, int* __restrict__ out) {
    u64 ti = 0, tj = 0;
    for (unsigned j = threadIdx.x; j < NBLK; j += TPB) {  // 16 coalesced uint2 loads
        uint2 p = ws[j];
        ti += p.x;
        tj += p.y;
    }
    for (int off = 32; off > 0; off >>= 1) {
        ti += __shfl_down(ti, off, 64);
        tj += __shfl_down(tj, off, 64);
    }
    __shared__ u64 s_i[4], s_j[4];
    const int wave = threadIdx.x >> 6;
    const int lane = threadIdx.x & 63;
    if (lane == 0) { s_i[wave] = ti; s_j[wave] = tj; }
    __syncthreads();
    if (threadIdx.x == 0) {
        u64 a = s_i[0] + s_i[1] + s_i[2] + s_i[3];
        u64 b = s_j[0] + s_j[1] + s_j[2] + s_j[3];
        out[0] = (int)(unsigned)(a & 0xFFFFFFFFull);  // int64 -> int32 wrap
        out[1] = (int)(unsigned)(b & 0xFFFFFFFFull);
    }
}

extern "C" void kernel_launch(void* const* d_in, const int* in_sizes, int n_in,
                              void* d_out, int out_size, void* d_ws, size_t ws_size,
                              hipStream_t stream) {
    const float4* in = (const float4*)d_in[0];
    uint2* ws = (uint2*)d_ws;   // needs 4096*8 = 32 KB of scratch
    int* out = (int*)d_out;

    // No memset needed: every ws slot is overwritten by nz_main each call.
    nz_main<<<NBLK, TPB, 0, stream>>>(in, ws);
    nz_finalize<<<1, TPB, 0, stream>>>(ws, out);
}